// Round 1
// baseline (1049.192 us; speedup 1.0000x reference)
//
#include <hip/hip_runtime.h>

// Problem constants (fixed by the reference).
#define N_FEAT  200000
#define DIM     512
#define KPROTO  64
#define CHUNK   32
#define NCHUNKS (N_FEAT / CHUNK)   // 6250, exact
#define APITCH  520                // f16 elems per LDS row: 1040B -> 2-way bank alias (free)
#define SPITCH  65                 // sims pitch: 65 dwords -> conflict-free row scans

typedef _Float16 f16;
typedef _Float16 f16x8 __attribute__((ext_vector_type(8)));
typedef _Float16 f16x4 __attribute__((ext_vector_type(4)));
typedef float    f32x4 __attribute__((ext_vector_type(4)));

// ws layout (bytes):
//   [0,      65536)  : p_h   f16  [64][512]   normalized prototypes
//   [65536,  196608) : sums  f32  [64][512]   segment sums (atomic target)
//   [196608, 196864) : counts int [64]
//   [196864, 396864) : asg   u8   [200000]

// ---------------------------------------------------------------- proto prep
__global__ __launch_bounds__(256) void proto_prep(const float* __restrict__ P,
                                                  f16* __restrict__ Ph) {
    __shared__ float red[4];
    __shared__ float s_scale;
    int k = blockIdx.x;
    int t = threadIdx.x;
    const float* row = P + k * DIM;
    float a = row[t], b = row[t + 256];
    float ss = a * a + b * b;
    #pragma unroll
    for (int off = 32; off; off >>= 1) ss += __shfl_down(ss, off);
    int lane = t & 63, wid = t >> 6;
    if (lane == 0) red[wid] = ss;
    __syncthreads();
    if (t == 0) {
        float tot = red[0] + red[1] + red[2] + red[3];
        s_scale = 1.0f / fmaxf(sqrtf(tot), 1e-8f);
    }
    __syncthreads();
    float sc = s_scale;
    Ph[k * DIM + t]       = (f16)(a * sc);
    Ph[k * DIM + t + 256] = (f16)(b * sc);
}

// ---------------------------------------------------------------- assignment
// Block = 256 thr (4 waves). Wave w owns proto tile [w*16, w*16+16).
// Per iter: stage 32 rows fp32->f16 in LDS, 2 rowtiles x 16 ksteps of
// mfma_f32_16x16x32_f16, sims -> LDS, threads 0..31 argmax their row.
__global__ __launch_bounds__(256) void assign_k(const float* __restrict__ F,
                                                const f16* __restrict__ Ph,
                                                unsigned char* __restrict__ asg,
                                                int* __restrict__ counts) {
    __shared__ f16   Al[CHUNK * APITCH];    // 33280 B
    __shared__ float sims[CHUNK * SPITCH];  //  8320 B
    __shared__ int   hist[KPROTO];

    int t    = threadIdx.x;
    int lane = t & 63;
    int wid  = t >> 6;       // wave id = proto tile
    int cq   = lane >> 4;    // quad
    int cl   = lane & 15;

    if (t < KPROTO) hist[t] = 0;

    // B fragments resident in registers: B[n = wid*16+cl][k = cq*8 + ks*32 + j]
    f16x8 bfrag[16];
    {
        const f16* pb = Ph + (wid * 16 + cl) * DIM + cq * 8;
        #pragma unroll
        for (int ks = 0; ks < 16; ++ks)
            bfrag[ks] = *(const f16x8*)(pb + ks * 32);
    }
    __syncthreads();

    for (int ch = blockIdx.x; ch < NCHUNKS; ch += gridDim.x) {
        // ---- stage 32 rows: 8 threads/row, each thread 16 contiguous float4
        {
            int r  = t >> 3;   // 0..31
            int c8 = t & 7;
            const float* src = F + (size_t)(ch * CHUNK + r) * DIM;
            f16* dst = Al + r * APITCH;
            #pragma unroll
            for (int j = 0; j < 16; ++j) {
                int cf4 = c8 + j * 8;              // float4 index 0..127
                f32x4 v = *(const f32x4*)(src + cf4 * 4);
                f16x4 h;
                h.x = (f16)v.x; h.y = (f16)v.y; h.z = (f16)v.z; h.w = (f16)v.w;
                *(f16x4*)(dst + cf4 * 4) = h;
            }
        }
        __syncthreads();

        // ---- MFMA: 2 rowtiles of 16 rows
        #pragma unroll
        for (int rt = 0; rt < 2; ++rt) {
            f32x4 acc = {0.f, 0.f, 0.f, 0.f};
            const f16* arow = Al + (rt * 16 + cl) * APITCH + cq * 8;
            #pragma unroll
            for (int ks = 0; ks < 16; ++ks) {
                f16x8 a = *(const f16x8*)(arow + ks * 32);
                acc = __builtin_amdgcn_mfma_f32_16x16x32_f16(a, bfrag[ks], acc, 0, 0, 0);
            }
            // D layout: col = lane&15, row = quad*4 + reg
            #pragma unroll
            for (int r = 0; r < 4; ++r) {
                int row = rt * 16 + cq * 4 + r;
                sims[row * SPITCH + wid * 16 + cl] = acc[r];
            }
        }
        __syncthreads();

        // ---- argmax per row (first-max tie-break, matches jnp.argmax)
        if (t < CHUNK) {
            const float* srow = sims + t * SPITCH;
            float best = srow[0];
            int bi = 0;
            #pragma unroll 8
            for (int j = 1; j < KPROTO; ++j) {
                float v = srow[j];
                if (v > best) { best = v; bi = j; }
            }
            asg[ch * CHUNK + t] = (unsigned char)bi;
            atomicAdd(&hist[bi], 1);
        }
        // next iter's stage writes Al (MFMA reads done at sync above);
        // argmax reads sims, overwritten only after next post-stage sync.
    }
    __syncthreads();
    if (t < KPROTO) atomicAdd(&counts[t], hist[t]);
}

// ---------------------------------------------------------------- segment sum
// Column-sliced: block handles 128 of 512 dims -> 32 KB LDS acc, 4 blocks/CU.
__global__ __launch_bounds__(256) void segsum_k(const float* __restrict__ F,
                                                const unsigned char* __restrict__ asg,
                                                float* __restrict__ sums,
                                                int groups) {
    __shared__ float acc[KPROTO * 128];   // 32 KB
    int t     = threadIdx.x;
    int slice = blockIdx.x & 3;
    int group = blockIdx.x >> 2;
    #pragma unroll
    for (int m = 0; m < 32; ++m) acc[t + m * 256] = 0.0f;
    __syncthreads();

    int lane = t & 63, wid = t >> 6;
    int stride = groups * 4;              // total waves in this slice family
    const float2* F2 = (const float2*)F;  // row pitch = 256 float2
    int colbase = slice * 64 + lane;

    for (int row = group * 4 + wid; row < N_FEAT; row += 4 * stride) {
        float2 v[4];
        int a[4];
        #pragma unroll
        for (int u = 0; u < 4; ++u) {
            int r = row + u * stride;
            if (r < N_FEAT) {
                a[u] = asg[r];
                v[u] = F2[(size_t)r * 256 + colbase];
            } else a[u] = -1;
        }
        #pragma unroll
        for (int u = 0; u < 4; ++u) {
            if (a[u] >= 0) {
                float* p = acc + a[u] * 128 + lane * 2;
                atomicAdd(p,     v[u].x);   // ds_add_f32, 2-way bank (free)
                atomicAdd(p + 1, v[u].y);
            }
        }
    }
    __syncthreads();
    #pragma unroll
    for (int m = 0; m < 32; ++m) {
        int idx = t + m * 256;            // 0..8191
        int k = idx >> 7, i = idx & 127;
        atomicAdd(&sums[k * DIM + slice * 128 + i], acc[idx]);
    }
}

// ---------------------------------------------------------------- EMA epilogue
__global__ __launch_bounds__(256) void ema_k(const float* __restrict__ P,
                                             const float* __restrict__ sums,
                                             const int* __restrict__ counts,
                                             float* __restrict__ out) {
    int idx = blockIdx.x * 256 + threadIdx.x;   // 0..32767
    int k = idx >> 9;
    float p = P[idx];
    int c = counts[k];
    float o = p;
    if (c > 0) o = 0.9f * p + 0.1f * (sums[idx] / (float)c);
    out[idx] = o;
}

// ---------------------------------------------------------------- launch
extern "C" void kernel_launch(void* const* d_in, const int* in_sizes, int n_in,
                              void* d_out, int out_size, void* d_ws, size_t ws_size,
                              hipStream_t stream) {
    const float* F = (const float*)d_in[0];   // [200000][512]
    const float* P = (const float*)d_in[1];   // [64][512]
    char* ws = (char*)d_ws;
    f16*   Ph     = (f16*)ws;
    float* sums   = (float*)(ws + 65536);
    int*   counts = (int*)(ws + 196608);
    unsigned char* asg = (unsigned char*)(ws + 196864);
    float* out = (float*)d_out;

    // zero sums + counts (contiguous region)
    hipMemsetAsync(sums, 0, KPROTO * DIM * sizeof(float) + KPROTO * sizeof(int), stream);

    proto_prep<<<KPROTO, 256, 0, stream>>>(P, Ph);
    assign_k<<<768, 256, 0, stream>>>(F, Ph, asg, counts);
    int groups = 256;                                    // grid = 1024
    segsum_k<<<groups * 4, 256, 0, stream>>>(F, asg, sums, groups);
    ema_k<<<(KPROTO * DIM) / 256, 256, 0, stream>>>(P, sums, counts, out);
}